// Round 9
// baseline (173.279 us; speedup 1.0000x reference)
//
#include <hip/hip_runtime.h>

// SSIM (skimage default): 7x7 uniform filter, valid crop (pad=3), sample cov.
// Images: 4096x4096 fp32, output region 4090x4090, result = mean(S) scalar.
//
// R9 = R4's proven skeleton + R8's verified epilogue algebra ONLY.
// Codegen rules learned R1-R8 (do not violate):
//  - runtime `rows_in` guards per row are load-bearing scheduler fences
//    (without them the AGPR ring spills 0.4-1.2 GB: R1/R2);
//  - NO load/consume liveness across or widening of guarded regions: R6
//    (copy-prefetch) +2us, R7 (cross-block ping-pong) +18us stall, R8
//    (16-load pair region) +19us stall. Single-row 8-load regions give a
//    stable ~34us stall; restructuring only ever raised it.
//  - epilogue algebra (R8, verified absmax 0.0): scale A1,B1 by 49^2 and
//    A2,B2 by 48*49 (ratio invariant) -> 11 ops/px, no 1/49 or covn muls;
//    fold the 2 pixels over one v_rcp_f32. Cut VALU-issue 40.2 -> 31.2us.
// Occupancy note: VGPR_Count ~68 excludes the ~80-reg AGPR ring; unified
// footprint ~148 caps us at ~3 waves/SIMD (~28% occ) - structural.
// History: R0 92 -> R4 74.5 -> R5 107(bad bundle) -> R6 76.5 -> R7 92 ->
// R8 84 (VALU 31us proven, pairing stall +19us). Expect R9 ~63-68us.

#define W_IMG   4096
#define H_IMG   4096
#define OW      4090
#define OH      4090
#define ROWS    10            // output rows per block strip; divides 4090
#define NTHR    256           // threads per block
#define CPB     512           // output columns per block (2 per thread)

__device__ __forceinline__ void hsums(const float* __restrict__ pO,
                                      const float* __restrict__ pT,
                                      float h[10])
{
    // load 8 consecutive floats of each image (8B-aligned: col0 is even)
    float2 a0 = *(const float2*)(pO + 0);
    float2 a1 = *(const float2*)(pO + 2);
    float2 a2 = *(const float2*)(pO + 4);
    float2 a3 = *(const float2*)(pO + 6);
    float2 b0 = *(const float2*)(pT + 0);
    float2 b1 = *(const float2*)(pT + 2);
    float2 b2 = *(const float2*)(pT + 4);
    float2 b3 = *(const float2*)(pT + 6);
    float o0=a0.x,o1=a0.y,o2=a1.x,o3=a1.y,o4=a2.x,o5=a2.y,o6=a3.x,o7=a3.y;
    float t0=b0.x,t1=b0.y,t2=b1.x,t3=b1.y,t4=b2.x,t5=b2.y,t6=b3.x,t7=b3.y;

    float so  = ((o0+o1)+(o2+o3)) + ((o4+o5)+o6);
    float st  = ((t0+t1)+(t2+t3)) + ((t4+t5)+t6);
    float soo = fmaf(o6,o6, fmaf(o5,o5, fmaf(o4,o4, fmaf(o3,o3, fmaf(o2,o2, fmaf(o1,o1, o0*o0))))));
    float stt = fmaf(t6,t6, fmaf(t5,t5, fmaf(t4,t4, fmaf(t3,t3, fmaf(t2,t2, fmaf(t1,t1, t0*t0))))));
    float sot = fmaf(o6,t6, fmaf(o5,t5, fmaf(o4,t4, fmaf(o3,t3, fmaf(o2,t2, fmaf(o1,t1, o0*t0))))));

    h[0] = so;   h[1] = so  - o0    + o7;
    h[2] = st;   h[3] = st  - t0    + t7;
    h[4] = soo;  h[5] = soo - o0*o0 + o7*o7;
    h[6] = stt;  h[7] = stt - t0*t0 + t7*t7;
    h[8] = sot;  h[9] = sot - o0*t0 + o7*t7;
}

// Scaled SSIM numerator/denominator. Exact ratio-preserving rescale:
//   A1,B1 *= 49^2 ; A2,B2 *= 48*49.  K1=C1*2401, K2=C2*2352.
__device__ __forceinline__ void ssim_nd(const float v[10], int px,
                                        float& num, float& den)
{
    const float K1 = 0.9604f;     // 4.0e-4 * 2401
    const float K2 = 8.4672f;     // 3.6e-3 * 2352
    float so  = v[0+px], st  = v[2+px];
    float soo = v[4+px], stt = v[6+px], sot = v[8+px];
    float t1 = so*st;
    float A1 = fmaf(2.0f, t1, K1);
    float ss = fmaf(st, st, so*so);               // so^2+st^2
    float B1 = ss + K1;
    float A2 = fmaf(98.0f, sot, fmaf(-2.0f, t1, K2));
    float B2 = fmaf(49.0f, soo + stt, K2 - ss);
    num = A1*A2;
    den = B1*B2;
}

__global__ __launch_bounds__(NTHR, 3)
void ssim_main(const float* __restrict__ O, const float* __restrict__ T,
               float* __restrict__ accp)
{
    const int t  = threadIdx.x;
    const int c0 = blockIdx.x * CPB + 2*t;     // first of the 2 output cols
    const int r0 = blockIdx.y * ROWS;          // first output row of strip
    const int rows_in = min(ROWS, OH - r0);    // runtime to the compiler!

    float acc = 0.0f;

    if (c0 < OW) {  // c0 even, OW even -> both pixels valid together
        const float* baseO = O + (size_t)r0 * W_IMG + c0;
        const float* baseT = T + (size_t)r0 * W_IMG + c0;

        float ring[7][10];   // 7-row delay line of horizontal sums (AGPRs)
        float v[10];         // running vertical sums over the 7-row window
        #pragma unroll
        for (int q = 0; q < 10; q++) v[q] = 0.0f;

        // warm-up: input rows 0..5
        #pragma unroll
        for (int i = 0; i < 6; i++) {
            float h[10];
            hsums(baseO + (size_t)i * W_IMG, baseT + (size_t)i * W_IMG, h);
            #pragma unroll
            for (int q = 0; q < 10; q++) { v[q] += h[q]; ring[i][q] = h[q]; }
        }

        // steady: output row j (input row i = j+6); chunked by 7 so ring
        // slot indices are compile-time constants (stays in VGPRs/AGPRs).
        for (int jb = 0; jb < ROWS; jb += 7) {
            #pragma unroll
            for (int u = 0; u < 7; u++) {
                const int j = jb + u;
                if (j < rows_in) {
                    const int i = j + 6;
                    float h[10];
                    hsums(baseO + (size_t)i * W_IMG,
                          baseT + (size_t)i * W_IMG, h);
                    #pragma unroll
                    for (int q = 0; q < 10; q++) v[q] += h[q];
                    // window now covers rows [j, j+6]
                    float n0, d0, n1, d1;
                    ssim_nd(v, 0, n0, d0);
                    ssim_nd(v, 1, n1, d1);
                    // one quarter-rate rcp for both pixels
                    acc = fmaf(fmaf(n0, d1, n1*d0),
                               __builtin_amdgcn_rcpf(d0*d1), acc);
                    // drop row i-6 (slot (i+1)%7 == u), store row i (slot i%7)
                    #pragma unroll
                    for (int q = 0; q < 10; q++) {
                        v[q] -= ring[u][q];
                        ring[(u + 6) % 7][q] = h[q];
                    }
                }
            }
        }
    }

    // wave(64) shuffle reduction
    #pragma unroll
    for (int off = 32; off; off >>= 1) acc += __shfl_down(acc, off);

    __shared__ float wpart[NTHR / 64];
    if ((t & 63) == 0) wpart[t >> 6] = acc;
    __syncthreads();
    if (t == 0) {
        float s = 0.0f;
        #pragma unroll
        for (int w = 0; w < NTHR / 64; w++) s += wpart[w];
        atomicAdd(accp, s);   // one atomic per block (3272 total)
    }
}

__global__ void ssim_final(const float* __restrict__ accp, float* __restrict__ out)
{
    out[0] = accp[0] * (float)(1.0 / ((double)OW * (double)OH));
}

extern "C" void kernel_launch(void* const* d_in, const int* in_sizes, int n_in,
                              void* d_out, int out_size, void* d_ws, size_t ws_size,
                              hipStream_t stream)
{
    const float* O = (const float*)d_in[0];
    const float* T = (const float*)d_in[1];
    float* out = (float*)d_out;
    float* acc = (float*)d_ws;

    hipMemsetAsync(acc, 0, sizeof(float), stream);   // ws is re-poisoned to 0xAA

    dim3 grid((OW + CPB - 1) / CPB, OH / ROWS);      // (8, 409)
    ssim_main<<<grid, NTHR, 0, stream>>>(O, T, acc);
    ssim_final<<<1, 1, 0, stream>>>(acc, out);
}

// Round 10
// 173.089 us; speedup vs baseline: 1.0011x; 1.0011x over previous
//
#include <hip/hip_runtime.h>

// SSIM (skimage default): 7x7 uniform filter, valid crop (pad=3), sample cov.
// Images: 4096x4096 fp32, output region 4090x4090, result = mean(S) scalar.
//
// R10 = R9's kernel body EXACTLY (best: 72us, VGPR 72, zero spill) + the
// ssim_final dispatch removed: blocks atomicAdd their pre-scaled partial
// straight into d_out (d_out is memset to 0 instead of ws). Ledger shows
// harness dur ~= ssim_main + 90-100us fixed overhead across R0-R9; one
// fewer dispatch in the timed graph is the only zero-risk cut available.
// absmax may move 0.0 -> ~1e-8 (per-block scaling rounds differently).
//
// Codegen rules learned R1-R8 (do not violate):
//  - runtime `rows_in` guards per row are load-bearing scheduler fences
//    (without them the AGPR ring spills 0.4-1.2 GB: R1/R2);
//  - NO load/consume liveness across or widening of guarded regions: R6
//    (copy-prefetch) +2us, R7 (cross-block ping-pong) +18us stall, R8
//    (16-load pair region) +19us stall. Single-row 8-load regions only.
//  - epilogue algebra (R8/R9, verified): A1,B1 scaled by 49^2, A2,B2 by
//    48*49 (ratio invariant) -> 11 ops/px; 2 pixels folded over one rcp.
// Occupancy note: VGPR_Count 72 excludes the ~80-reg AGPR ring; unified
// footprint ~150 caps us at 3 waves/SIMD (~28% occ) - structural.
// History: R0 92 -> R4 74.5 -> R5 107 -> R6 76.5 -> R7 92 -> R8 84 ->
// R9 72.2 (VALU-issue 33us, stall 39us, stall-dominant).

#define W_IMG   4096
#define H_IMG   4096
#define OW      4090
#define OH      4090
#define ROWS    10            // output rows per block strip; divides 4090
#define NTHR    256           // threads per block
#define CPB     512           // output columns per block (2 per thread)

__device__ __forceinline__ void hsums(const float* __restrict__ pO,
                                      const float* __restrict__ pT,
                                      float h[10])
{
    // load 8 consecutive floats of each image (8B-aligned: col0 is even)
    float2 a0 = *(const float2*)(pO + 0);
    float2 a1 = *(const float2*)(pO + 2);
    float2 a2 = *(const float2*)(pO + 4);
    float2 a3 = *(const float2*)(pO + 6);
    float2 b0 = *(const float2*)(pT + 0);
    float2 b1 = *(const float2*)(pT + 2);
    float2 b2 = *(const float2*)(pT + 4);
    float2 b3 = *(const float2*)(pT + 6);
    float o0=a0.x,o1=a0.y,o2=a1.x,o3=a1.y,o4=a2.x,o5=a2.y,o6=a3.x,o7=a3.y;
    float t0=b0.x,t1=b0.y,t2=b1.x,t3=b1.y,t4=b2.x,t5=b2.y,t6=b3.x,t7=b3.y;

    float so  = ((o0+o1)+(o2+o3)) + ((o4+o5)+o6);
    float st  = ((t0+t1)+(t2+t3)) + ((t4+t5)+t6);
    float soo = fmaf(o6,o6, fmaf(o5,o5, fmaf(o4,o4, fmaf(o3,o3, fmaf(o2,o2, fmaf(o1,o1, o0*o0))))));
    float stt = fmaf(t6,t6, fmaf(t5,t5, fmaf(t4,t4, fmaf(t3,t3, fmaf(t2,t2, fmaf(t1,t1, t0*t0))))));
    float sot = fmaf(o6,t6, fmaf(o5,t5, fmaf(o4,t4, fmaf(o3,t3, fmaf(o2,t2, fmaf(o1,t1, o0*t0))))));

    h[0] = so;   h[1] = so  - o0    + o7;
    h[2] = st;   h[3] = st  - t0    + t7;
    h[4] = soo;  h[5] = soo - o0*o0 + o7*o7;
    h[6] = stt;  h[7] = stt - t0*t0 + t7*t7;
    h[8] = sot;  h[9] = sot - o0*t0 + o7*t7;
}

// Scaled SSIM numerator/denominator. Exact ratio-preserving rescale:
//   A1,B1 *= 49^2 ; A2,B2 *= 48*49.  K1=C1*2401, K2=C2*2352.
__device__ __forceinline__ void ssim_nd(const float v[10], int px,
                                        float& num, float& den)
{
    const float K1 = 0.9604f;     // 4.0e-4 * 2401
    const float K2 = 8.4672f;     // 3.6e-3 * 2352
    float so  = v[0+px], st  = v[2+px];
    float soo = v[4+px], stt = v[6+px], sot = v[8+px];
    float t1 = so*st;
    float A1 = fmaf(2.0f, t1, K1);
    float ss = fmaf(st, st, so*so);               // so^2+st^2
    float B1 = ss + K1;
    float A2 = fmaf(98.0f, sot, fmaf(-2.0f, t1, K2));
    float B2 = fmaf(49.0f, soo + stt, K2 - ss);
    num = A1*A2;
    den = B1*B2;
}

__global__ __launch_bounds__(NTHR, 3)
void ssim_main(const float* __restrict__ O, const float* __restrict__ T,
               float* __restrict__ outp)
{
    const int t  = threadIdx.x;
    const int c0 = blockIdx.x * CPB + 2*t;     // first of the 2 output cols
    const int r0 = blockIdx.y * ROWS;          // first output row of strip
    const int rows_in = min(ROWS, OH - r0);    // runtime to the compiler!

    float acc = 0.0f;

    if (c0 < OW) {  // c0 even, OW even -> both pixels valid together
        const float* baseO = O + (size_t)r0 * W_IMG + c0;
        const float* baseT = T + (size_t)r0 * W_IMG + c0;

        float ring[7][10];   // 7-row delay line of horizontal sums (AGPRs)
        float v[10];         // running vertical sums over the 7-row window
        #pragma unroll
        for (int q = 0; q < 10; q++) v[q] = 0.0f;

        // warm-up: input rows 0..5
        #pragma unroll
        for (int i = 0; i < 6; i++) {
            float h[10];
            hsums(baseO + (size_t)i * W_IMG, baseT + (size_t)i * W_IMG, h);
            #pragma unroll
            for (int q = 0; q < 10; q++) { v[q] += h[q]; ring[i][q] = h[q]; }
        }

        // steady: output row j (input row i = j+6); chunked by 7 so ring
        // slot indices are compile-time constants (stays in VGPRs/AGPRs).
        for (int jb = 0; jb < ROWS; jb += 7) {
            #pragma unroll
            for (int u = 0; u < 7; u++) {
                const int j = jb + u;
                if (j < rows_in) {
                    const int i = j + 6;
                    float h[10];
                    hsums(baseO + (size_t)i * W_IMG,
                          baseT + (size_t)i * W_IMG, h);
                    #pragma unroll
                    for (int q = 0; q < 10; q++) v[q] += h[q];
                    // window now covers rows [j, j+6]
                    float n0, d0, n1, d1;
                    ssim_nd(v, 0, n0, d0);
                    ssim_nd(v, 1, n1, d1);
                    // one quarter-rate rcp for both pixels
                    acc = fmaf(fmaf(n0, d1, n1*d0),
                               __builtin_amdgcn_rcpf(d0*d1), acc);
                    // drop row i-6 (slot (i+1)%7 == u), store row i (slot i%7)
                    #pragma unroll
                    for (int q = 0; q < 10; q++) {
                        v[q] -= ring[u][q];
                        ring[(u + 6) % 7][q] = h[q];
                    }
                }
            }
        }
    }

    // wave(64) shuffle reduction
    #pragma unroll
    for (int off = 32; off; off >>= 1) acc += __shfl_down(acc, off);

    __shared__ float wpart[NTHR / 64];
    if ((t & 63) == 0) wpart[t >> 6] = acc;
    __syncthreads();
    if (t == 0) {
        float s = 0.0f;
        #pragma unroll
        for (int w = 0; w < NTHR / 64; w++) s += wpart[w];
        // pre-scaled atomic straight into the output scalar: removes the
        // ssim_final dispatch from the timed graph (one atomic per block).
        const float inv = (float)(1.0 / ((double)OW * (double)OH));
        atomicAdd(outp, s * inv);
    }
}

extern "C" void kernel_launch(void* const* d_in, const int* in_sizes, int n_in,
                              void* d_out, int out_size, void* d_ws, size_t ws_size,
                              hipStream_t stream)
{
    const float* O = (const float*)d_in[0];
    const float* T = (const float*)d_in[1];
    float* out = (float*)d_out;

    hipMemsetAsync(out, 0, sizeof(float), stream);   // accumulate in d_out

    dim3 grid((OW + CPB - 1) / CPB, OH / ROWS);      // (8, 409)
    ssim_main<<<grid, NTHR, 0, stream>>>(O, T, out);
}

// Round 11
// 169.085 us; speedup vs baseline: 1.0248x; 1.0237x over previous
//
#include <hip/hip_runtime.h>

// SSIM (skimage default): 7x7 uniform filter, valid crop (pad=3), sample cov.
// Images: 4096x4096 fp32, output region 4090x4090, result = mean(S) scalar.
//
// R11: 4 output columns per thread (was 2). Mechanism: per row-iteration the
// compiler drains vmcnt once (proven irreducible: R6 copy-prefetch, R7
// cross-block ping-pong, R8 pair regions ALL regressed); 4px/thread halves
// the global iteration count (grid 8x409 -> 4x409) so the fixed per-iter
// stall amortizes over 2x outputs. Also -19% VALU/output via rolling
// horizontal sums (10 loaded floats serve 4 windows: base + 3 increments).
//  - per-row guarded single-region structure UNCHANGED (codegen rules
//    R1-R8: runtime rows_in guards; loads consumed in issuing region).
//  - ring doubles to [7][20] (AGPR-resident; unified footprint ~230 under
//    __launch_bounds__(256,2) cap 256). Falsifier: WRITE_SIZE>10MB = spill.
//  - boundary: OW=4090=1022*4+2 -> last active thread clamps c0 to OW-4
//    (loads stay <= col 4095, no OOB) and masks its 2 duplicate pixels.
// History: R0 92 -> R4 74.5 -> R9/R10 72 (VALU 33us + stall 39us);
// R10 showed harness-kernel gap (~100us) is graph-fixed, not dispatches.

#define W_IMG   4096
#define H_IMG   4096
#define OW      4090
#define OH      4090
#define ROWS    10            // output rows per block strip; divides 4090
#define NTHR    256           // threads per block
#define CPB     1024          // output columns per block (4 per thread)

// 10 consecutive floats per image -> h sums for 4 windows.
// Layout: h[0..3]=so, h[4..7]=st, h[8..11]=soo, h[12..15]=stt, h[16..19]=sot.
__device__ __forceinline__ void hsums4(const float* __restrict__ pO,
                                       const float* __restrict__ pT,
                                       float h[20])
{
    float x[10], y[10];
    #pragma unroll
    for (int k = 0; k < 5; k++) {
        float2 a = *(const float2*)(pO + 2*k);
        float2 b = *(const float2*)(pT + 2*k);
        x[2*k] = a.x; x[2*k+1] = a.y;
        y[2*k] = b.x; y[2*k+1] = b.y;
    }
    // plain sums (base over cols 0..6, then roll)
    h[0] = ((x[0]+x[1])+(x[2]+x[3])) + ((x[4]+x[5])+x[6]);
    h[1] = h[0] - x[0] + x[7];
    h[2] = h[1] - x[1] + x[8];
    h[3] = h[2] - x[2] + x[9];
    h[4] = ((y[0]+y[1])+(y[2]+y[3])) + ((y[4]+y[5])+y[6]);
    h[5] = h[4] - y[0] + y[7];
    h[6] = h[5] - y[1] + y[8];
    h[7] = h[6] - y[2] + y[9];
    // squares O
    h[8]  = fmaf(x[6],x[6], fmaf(x[5],x[5], fmaf(x[4],x[4], fmaf(x[3],x[3], fmaf(x[2],x[2], fmaf(x[1],x[1], x[0]*x[0]))))));
    h[9]  = fmaf(x[7],x[7], h[8]  - x[0]*x[0]);
    h[10] = fmaf(x[8],x[8], h[9]  - x[1]*x[1]);
    h[11] = fmaf(x[9],x[9], h[10] - x[2]*x[2]);
    // squares T
    h[12] = fmaf(y[6],y[6], fmaf(y[5],y[5], fmaf(y[4],y[4], fmaf(y[3],y[3], fmaf(y[2],y[2], fmaf(y[1],y[1], y[0]*y[0]))))));
    h[13] = fmaf(y[7],y[7], h[12] - y[0]*y[0]);
    h[14] = fmaf(y[8],y[8], h[13] - y[1]*y[1]);
    h[15] = fmaf(y[9],y[9], h[14] - y[2]*y[2]);
    // cross
    h[16] = fmaf(x[6],y[6], fmaf(x[5],y[5], fmaf(x[4],y[4], fmaf(x[3],y[3], fmaf(x[2],y[2], fmaf(x[1],y[1], x[0]*y[0]))))));
    h[17] = fmaf(x[7],y[7], h[16] - x[0]*y[0]);
    h[18] = fmaf(x[8],y[8], h[17] - x[1]*y[1]);
    h[19] = fmaf(x[9],y[9], h[18] - x[2]*y[2]);
}

// Scaled SSIM numerator/denominator (R8/R9 verified algebra):
//   A1,B1 *= 49^2 ; A2,B2 *= 48*49 (ratio invariant).
__device__ __forceinline__ void ssim_nd(const float v[20], int px,
                                        float& num, float& den)
{
    const float K1 = 0.9604f;     // 4.0e-4 * 2401
    const float K2 = 8.4672f;     // 3.6e-3 * 2352
    float so  = v[px],    st  = v[4+px];
    float soo = v[8+px],  stt = v[12+px], sot = v[16+px];
    float t1 = so*st;
    float A1 = fmaf(2.0f, t1, K1);
    float ss = fmaf(st, st, so*so);
    float B1 = ss + K1;
    float A2 = fmaf(98.0f, sot, fmaf(-2.0f, t1, K2));
    float B2 = fmaf(49.0f, soo + stt, K2 - ss);
    num = A1*A2;
    den = B1*B2;
}

__global__ __launch_bounds__(NTHR, 2)
void ssim_main(const float* __restrict__ O, const float* __restrict__ T,
               float* __restrict__ outp)
{
    const int t  = threadIdx.x;
    const int nominal = blockIdx.x * CPB + 4*t;   // first of 4 output cols
    const int r0 = blockIdx.y * ROWS;             // first output row of strip
    const int rows_in = min(ROWS, OH - r0);       // runtime to the compiler!

    float acc = 0.0f;

    if (nominal < OW) {
        // clamp so the 10-float load never passes col 4095; the (<=2)
        // duplicated leading pixels are masked out of the accumulation.
        const int c0   = min(nominal, OW - 4);     // stays even
        const float w01 = (nominal == c0) ? 1.0f : 0.0f;  // mask px0,px1

        const float* baseO = O + (size_t)r0 * W_IMG + c0;
        const float* baseT = T + (size_t)r0 * W_IMG + c0;

        float ring[7][20];   // 7-row delay line of horizontal sums (AGPRs)
        float v[20];         // running vertical sums over the 7-row window
        #pragma unroll
        for (int q = 0; q < 20; q++) v[q] = 0.0f;

        // warm-up: input rows 0..5
        #pragma unroll
        for (int i = 0; i < 6; i++) {
            float h[20];
            hsums4(baseO + (size_t)i * W_IMG, baseT + (size_t)i * W_IMG, h);
            #pragma unroll
            for (int q = 0; q < 20; q++) { v[q] += h[q]; ring[i][q] = h[q]; }
        }

        // steady: output row j (input row i = j+6); chunked by 7 so ring
        // slot indices are compile-time constants (stays in VGPRs/AGPRs).
        for (int jb = 0; jb < ROWS; jb += 7) {
            #pragma unroll
            for (int u = 0; u < 7; u++) {
                const int j = jb + u;
                if (j < rows_in) {
                    const int i = j + 6;
                    float h[20];
                    hsums4(baseO + (size_t)i * W_IMG,
                           baseT + (size_t)i * W_IMG, h);
                    #pragma unroll
                    for (int q = 0; q < 20; q++) v[q] += h[q];
                    // window now covers rows [j, j+6]
                    float n0,d0,n1,d1,n2,d2,n3,d3;
                    ssim_nd(v, 0, n0, d0);
                    ssim_nd(v, 1, n1, d1);
                    ssim_nd(v, 2, n2, d2);
                    ssim_nd(v, 3, n3, d3);
                    float s01 = fmaf(n0, d1, n1*d0) *
                                __builtin_amdgcn_rcpf(d0*d1);
                    float s23 = fmaf(n2, d3, n3*d2) *
                                __builtin_amdgcn_rcpf(d2*d3);
                    acc = fmaf(w01, s01, acc + s23);
                    // drop row i-6 (slot u), store row i (slot (u+6)%7)
                    #pragma unroll
                    for (int q = 0; q < 20; q++) {
                        v[q] -= ring[u][q];
                        ring[(u + 6) % 7][q] = h[q];
                    }
                }
            }
        }
    }

    // wave(64) shuffle reduction
    #pragma unroll
    for (int off = 32; off; off >>= 1) acc += __shfl_down(acc, off);

    __shared__ float wpart[NTHR / 64];
    if ((t & 63) == 0) wpart[t >> 6] = acc;
    __syncthreads();
    if (t == 0) {
        float s = 0.0f;
        #pragma unroll
        for (int w = 0; w < NTHR / 64; w++) s += wpart[w];
        // pre-scaled atomic straight into the output scalar (R10: one
        // kernel, no ssim_final dispatch).
        const float inv = (float)(1.0 / ((double)OW * (double)OH));
        atomicAdd(outp, s * inv);
    }
}

extern "C" void kernel_launch(void* const* d_in, const int* in_sizes, int n_in,
                              void* d_out, int out_size, void* d_ws, size_t ws_size,
                              hipStream_t stream)
{
    const float* O = (const float*)d_in[0];
    const float* T = (const float*)d_in[1];
    float* out = (float*)d_out;

    hipMemsetAsync(out, 0, sizeof(float), stream);   // accumulate in d_out

    dim3 grid((OW + CPB - 1) / CPB, OH / ROWS);      // (4, 409)
    ssim_main<<<grid, NTHR, 0, stream>>>(O, T, out);
}